// Round 5
// baseline (165.950 us; speedup 1.0000x reference)
//
#include <hip/hip_runtime.h>
#include <math.h>

constexpr int MM = 50;    // members per group
constexpr int DD = 64;    // embedding dim
constexpr int HH = 16;    // attention hidden
constexpr int PH = 8;     // predict hidden
constexpr int WPB = 4;    // waves per block
constexpr int RST = 72;   // f16 per LDS row (64 + 8 pad; 144B stride, bank-uniform)

typedef _Float16 half4_t  __attribute__((ext_vector_type(4)));
typedef _Float16 half8_t  __attribute__((ext_vector_type(8)));
typedef float    float4_t __attribute__((ext_vector_type(4)));

// ============================================================================
// Single fused kernel. Wave-per-sample.
//  1. Gather all 50 member rows (coalesced (member-sub, dim-chunk) split,
//     8 lanes/row x 32B) -> LDS f16 rows. Slots 50..63 = member 49 (real
//     data, weight 0) so MFMA tiles never see garbage.
//  2. Scores via 16x v_mfma_f32_16x16x16_f16: S[50,16] = U[50,64] @ W1a[64,16]
//     (4 M-tiles x 4 K-steps). A-frag: row=lane&15, k=(lane>>4)*4+e (ds_read_b64
//     from LDS). B-frag (W1a f16): col=lane&15, same k (global, L1-hot).
//     C/D: col=lane&15, row=(lane>>4)*4+reg  [m89-verified mapping].
//  3. ib = item @ W1b + b1 in fp32 (lane-per-dim + shfl reduce).
//     score[m] = b2 + sum_h relu(C[m,h]+ib[h])*w2[h]  (shfl over 16 h-lanes).
//  4. Softmax over 64 member slots (invalid -> -inf -> weight 0).
//  5. Pool from the SAME LDS rows (lane-per-dim), + group row, predict MLP.
// No workspace, no precompute kernel, one dispatch.
// ============================================================================
__global__ __launch_bounds__(256) void agree_mfma(
    const int* __restrict__ group_inputs,
    const int* __restrict__ item_inputs,
    const int* __restrict__ member_ids,
    const int* __restrict__ member_lengths,
    const float* __restrict__ user_table,
    const float* __restrict__ item_table,
    const float* __restrict__ group_table,
    const float* __restrict__ att_w1,   // [2D][H] row-major
    const float* __restrict__ att_b1,   // [H]
    const float* __restrict__ att_w2,   // [H]
    const float* __restrict__ att_b2,   // [1]
    const float* __restrict__ pred_w1,  // [3D][8]
    const float* __restrict__ pred_b1,  // [8]
    const float* __restrict__ pred_w2,  // [8]
    const float* __restrict__ pred_b2,  // [1]
    float* __restrict__ out,
    int B)
{
    __shared__ _Float16 rows [WPB][64][RST];  // 36864 B
    __shared__ int      idbuf[WPB][64];       //  1024 B
    __shared__ float    wt   [WPB][64];       //  1024 B

    const int lane = threadIdx.x & 63;
    const int wv   = threadIdx.x >> 6;
    const int b    = blockIdx.x * WPB + wv;
    if (b >= B) return;

    const int my_m  = (lane < MM) ? lane : (MM - 1);
    const int my_id = member_ids[b * MM + my_m];            // coalesced
    const int len      = member_lengths[b];                 // uniform
    const int item_idx = item_inputs[b];                    // uniform
    const int gid      = group_inputs[b];                   // uniform

    const float item_d = item_table[(unsigned)(item_idx * DD + lane)];
    const float grp_d  = group_table[(unsigned)(gid * DD + lane)];

    idbuf[wv][lane] = my_id;    // slots 50..63 carry member-49's id

    // ---- B-fragments of W1a (f16) + per-lane h-constants (L1-hot, hoisted)
    const int h = lane & 15;
    const int q = lane >> 4;
    half4_t bfrag[4];
    #pragma unroll
    for (int s = 0; s < 4; ++s) {
        #pragma unroll
        for (int e = 0; e < 4; ++e) {
            const int k = s * 16 + q * 4 + e;
            bfrag[s][e] = (_Float16)att_w1[k * HH + h];
        }
    }
    const float w2h = att_w2[h];
    const float b2  = att_b2[0];

    // ---- gather all 64 member-row slots -> LDS f16 (8 lanes per row, 32B each)
    const int gi = lane >> 3;       // member sub-index within chunk (0..7)
    const int gj = lane & 7;        // dim chunk: 8 fp32 = 32B -> 8 f16 = 16B
    __builtin_amdgcn_s_waitcnt(0);  // idbuf visible (own-wave LDS)
    int ids[8];
    #pragma unroll
    for (int c = 0; c < 8; ++c) ids[c] = idbuf[wv][c * 8 + gi];
    #pragma unroll
    for (int c = 0; c < 8; ++c) {
        const float4* rp =
            (const float4*)(user_table + (size_t)(unsigned)ids[c] * DD + gj * 8);
        const float4 a = rp[0];
        const float4 d = rp[1];
        half8_t hv;
        hv[0] = (_Float16)a.x;  hv[1] = (_Float16)a.y;
        hv[2] = (_Float16)a.z;  hv[3] = (_Float16)a.w;
        hv[4] = (_Float16)d.x;  hv[5] = (_Float16)d.y;
        hv[6] = (_Float16)d.z;  hv[7] = (_Float16)d.w;
        *(half8_t*)&rows[wv][c * 8 + gi][gj * 8] = hv;   // ds_write_b128
    }

    // ---- ib[j] = item @ W1b + b1 (fp32), then select this lane's ib[h]
    float hb[HH];
    {
        const float* w1b = att_w1 + (size_t)(DD + lane) * HH;
        #pragma unroll
        for (int j = 0; j < HH; ++j) hb[j] = item_d * w1b[j];
        #pragma unroll
        for (int off = 32; off > 0; off >>= 1) {
            #pragma unroll
            for (int j = 0; j < HH; ++j) hb[j] += __shfl_xor(hb[j], off, 64);
        }
        #pragma unroll
        for (int j = 0; j < HH; ++j) hb[j] += att_b1[j];
    }
    float ibh = hb[0];
    #pragma unroll
    for (int j = 1; j < HH; ++j) ibh = (h == j) ? hb[j] : ibh;

    // ---- MFMA: S = U @ W1a   (4 M-tiles x 4 K-steps of 16x16x16 f16)
    __builtin_amdgcn_s_waitcnt(0);  // row writes visible (own-wave LDS)
    float4_t acc[4] = {{0.f,0.f,0.f,0.f}, {0.f,0.f,0.f,0.f},
                       {0.f,0.f,0.f,0.f}, {0.f,0.f,0.f,0.f}};
    #pragma unroll
    for (int s = 0; s < 4; ++s) {
        #pragma unroll
        for (int t = 0; t < 4; ++t) {
            const half4_t a =
                *(const half4_t*)&rows[wv][t * 16 + h][s * 16 + q * 4]; // b64
            acc[t] = __builtin_amdgcn_mfma_f32_16x16x16f16(a, bfrag[s],
                                                           acc[t], 0, 0, 0);
        }
    }

    // ---- scores: reduce over h across the 16 lanes sharing q
    float sc[4][4];
    #pragma unroll
    for (int t = 0; t < 4; ++t) {
        #pragma unroll
        for (int r = 0; r < 4; ++r) {
            float v = fmaxf(acc[t][r] + ibh, 0.0f) * w2h;
            v += __shfl_xor(v, 1, 64);
            v += __shfl_xor(v, 2, 64);
            v += __shfl_xor(v, 4, 64);
            v += __shfl_xor(v, 8, 64);
            const int m = t * 16 + q * 4 + r;     // member slot
            const bool vmask = (m < MM) && (m <= len);
            sc[t][r] = vmask ? (v + b2) : -INFINITY;
        }
    }

    // ---- softmax over all 64 slots (each lane holds 16 distinct members)
    float mx = -INFINITY;
    #pragma unroll
    for (int t = 0; t < 4; ++t)
        #pragma unroll
        for (int r = 0; r < 4; ++r) mx = fmaxf(mx, sc[t][r]);
    mx = fmaxf(mx, __shfl_xor(mx, 16, 64));
    mx = fmaxf(mx, __shfl_xor(mx, 32, 64));

    float ew[4][4];
    float lsum = 0.0f;
    #pragma unroll
    for (int t = 0; t < 4; ++t) {
        #pragma unroll
        for (int r = 0; r < 4; ++r) {
            ew[t][r] = __expf(sc[t][r] - mx);     // exp(-inf)=0 for invalid
            lsum += ew[t][r];
        }
    }
    lsum += __shfl_xor(lsum, 16, 64);
    lsum += __shfl_xor(lsum, 32, 64);
    const float inv = 1.0f / lsum;

    if (h == 0) {   // one writer group per member set
        #pragma unroll
        for (int t = 0; t < 4; ++t)
            #pragma unroll
            for (int r = 0; r < 4; ++r)
                wt[wv][t * 16 + q * 4 + r] = ew[t][r] * inv;
    }
    __builtin_amdgcn_s_waitcnt(0);

    // ---- pool from LDS rows (lane-per-dim), weights broadcast
    const int mcnt = (len < MM - 1 ? len : MM - 1) + 1;   // 1..50, uniform
    float g = 0.0f;
    #pragma unroll 4
    for (int m = 0; m < mcnt; ++m)
        g = fmaf(wt[wv][m], (float)rows[wv][m][lane], g);
    g += grp_d;

    // ---- predict MLP: new_e = [g*item, g, item] (192 -> 8 -> 1), lane-per-d
    const float elem = g * item_d;
    float p[PH];
    {
        const float* pa = pred_w1 + (size_t)lane * PH;      // L1-hot
        const float* pb = pred_w1 + (size_t)(DD + lane) * PH;
        const float* pc = pred_w1 + (size_t)(2 * DD + lane) * PH;
        #pragma unroll
        for (int jj = 0; jj < PH; ++jj)
            p[jj] = fmaf(elem, pa[jj], fmaf(g, pb[jj], item_d * pc[jj]));
    }
    #pragma unroll
    for (int off = 32; off > 0; off >>= 1) {
        #pragma unroll
        for (int jj = 0; jj < PH; ++jj) p[jj] += __shfl_xor(p[jj], off, 64);
    }

    if (lane == 0) {
        float acc2 = pred_b2[0];
        #pragma unroll
        for (int jj = 0; jj < PH; ++jj)
            acc2 = fmaf(fmaxf(p[jj] + pred_b1[jj], 0.0f), pred_w2[jj], acc2);
        out[b] = 1.0f / (1.0f + __expf(-acc2));
    }
}

extern "C" void kernel_launch(void* const* d_in, const int* in_sizes, int n_in,
                              void* d_out, int out_size, void* d_ws, size_t ws_size,
                              hipStream_t stream) {
    const int*   group_inputs   = (const int*)d_in[0];
    const int*   item_inputs    = (const int*)d_in[1];
    const int*   member_ids     = (const int*)d_in[2];
    const int*   member_lengths = (const int*)d_in[3];
    const float* user_table     = (const float*)d_in[4];
    const float* item_table     = (const float*)d_in[5];
    const float* group_table    = (const float*)d_in[6];
    const float* att_w1         = (const float*)d_in[7];
    const float* att_b1         = (const float*)d_in[8];
    const float* att_w2         = (const float*)d_in[9];
    const float* att_b2         = (const float*)d_in[10];
    const float* pred_w1        = (const float*)d_in[11];
    const float* pred_b1        = (const float*)d_in[12];
    const float* pred_w2        = (const float*)d_in[13];
    const float* pred_b2        = (const float*)d_in[14];
    float* out = (float*)d_out;

    const int B = in_sizes[0];
    (void)d_ws; (void)ws_size;   // unused: fills are unconditional (r4 measured)

    const int blocks = (B + WPB - 1) / WPB;
    agree_mfma<<<blocks, 256, 0, stream>>>(
        group_inputs, item_inputs, member_ids, member_lengths,
        user_table, item_table, group_table,
        att_w1, att_b1, att_w2, att_b2,
        pred_w1, pred_b1, pred_w2, pred_b2,
        out, B);
}

// Round 6
// 154.920 us; speedup vs baseline: 1.0712x; 1.0712x over previous
//
#include <hip/hip_runtime.h>
#include <math.h>

constexpr int MM = 50;    // members per group
constexpr int DD = 64;    // embedding dim
constexpr int HH = 16;    // attention hidden
constexpr int PH = 8;     // predict hidden
constexpr int WPB = 4;    // waves per block
constexpr int RST = 72;   // f16 per LDS row (64 + 8 pad; 144B stride)

typedef _Float16 half4_t  __attribute__((ext_vector_type(4)));
typedef _Float16 half8_t  __attribute__((ext_vector_type(8)));
typedef float    float4_t __attribute__((ext_vector_type(4)));

// ============================================================================
// Single fused kernel, wave-per-sample. r6 changes vs r5 (latency-bound gather):
//  - VALID-ONLY gather: ceil(mcnt/8) chunks (mean 3.6 of 7), two-pass
//    predicated (issue all loads -> regs, then convert+ds_write) so all
//    loads are in flight together.
//  - member ids via __shfl (no idbuf LDS, no early full-drain waitcnt).
//  - NO explicit s_waitcnt(0): same-wave LDS is in-order; compiler inserts
//    counted vmcnt/lgkmcnt waits. r5's drains also blocked item/group loads.
//  - MFMA only on valid 16-row tiles (uniform branch). Stale LDS rows feed
//    masked-out scores only (row-independent MFMA), never pooled.
// ============================================================================
__global__ __launch_bounds__(256) void agree_mfma(
    const int* __restrict__ group_inputs,
    const int* __restrict__ item_inputs,
    const int* __restrict__ member_ids,
    const int* __restrict__ member_lengths,
    const float* __restrict__ user_table,
    const float* __restrict__ item_table,
    const float* __restrict__ group_table,
    const float* __restrict__ att_w1,   // [2D][H] row-major
    const float* __restrict__ att_b1,   // [H]
    const float* __restrict__ att_w2,   // [H]
    const float* __restrict__ att_b2,   // [1]
    const float* __restrict__ pred_w1,  // [3D][8]
    const float* __restrict__ pred_b1,  // [8]
    const float* __restrict__ pred_w2,  // [8]
    const float* __restrict__ pred_b2,  // [1]
    float* __restrict__ out,
    int B)
{
    __shared__ _Float16 rows[WPB][64][RST];  // 36864 B
    __shared__ float    wt  [WPB][64];       //  1024 B

    const int lane = threadIdx.x & 63;
    const int wv   = threadIdx.x >> 6;
    const int b    = blockIdx.x * WPB + wv;
    if (b >= B) return;

    const int my_m  = (lane < MM) ? lane : (MM - 1);
    const int my_id = member_ids[b * MM + my_m];            // coalesced
    const int len      = member_lengths[b];                 // uniform
    const int item_idx = item_inputs[b];                    // uniform
    const int gid      = group_inputs[b];                   // uniform

    const float item_d = item_table[(unsigned)(item_idx * DD + lane)];
    const float grp_d  = group_table[(unsigned)(gid * DD + lane)];

    const int mcnt = (len < MM - 1 ? len : MM - 1) + 1;     // 1..50, uniform
    const int gch  = (mcnt + 7) >> 3;                       // gather chunks 1..7
    const int nt   = (mcnt + 15) >> 4;                      // MFMA tiles 1..4

    // ---- pass 1: issue ALL valid gather loads (regs), fully in flight
    const int gi = lane >> 3;       // member sub-index within chunk (0..7)
    const int gj = lane & 7;        // dim chunk: 8 fp32 = 32B
    float4 ga[7], gd[7];
    #pragma unroll
    for (int c = 0; c < 7; ++c) {
        if (c < gch) {              // uniform branch
            const int id = __shfl(my_id, c * 8 + gi, 64);
            const float4* rp =
                (const float4*)(user_table + (size_t)(unsigned)id * DD + gj * 8);
            ga[c] = rp[0];
            gd[c] = rp[1];
        }
    }

    // ---- overlap gather latency: B-fragments of W1a + per-lane consts
    const int h = lane & 15;
    const int q = lane >> 4;
    half4_t bfrag[4];
    #pragma unroll
    for (int s = 0; s < 4; ++s) {
        #pragma unroll
        for (int e = 0; e < 4; ++e) {
            const int k = s * 16 + q * 4 + e;
            bfrag[s][e] = (_Float16)att_w1[k * HH + h];
        }
    }
    const float w2h = att_w2[h];
    const float b2  = att_b2[0];

    // ---- ib[j] = item @ W1b + b1 (fp32), select this lane's ib[h]
    float hb[HH];
    {
        const float* w1b = att_w1 + (size_t)(DD + lane) * HH;
        #pragma unroll
        for (int j = 0; j < HH; ++j) hb[j] = item_d * w1b[j];
        #pragma unroll
        for (int off = 32; off > 0; off >>= 1) {
            #pragma unroll
            for (int j = 0; j < HH; ++j) hb[j] += __shfl_xor(hb[j], off, 64);
        }
        #pragma unroll
        for (int j = 0; j < HH; ++j) hb[j] += att_b1[j];
    }
    float ibh = hb[0];
    #pragma unroll
    for (int j = 1; j < HH; ++j) ibh = (h == j) ? hb[j] : ibh;

    // ---- pass 2: convert + LDS write (counted vmcnt waits per chunk)
    #pragma unroll
    for (int c = 0; c < 7; ++c) {
        if (c < gch) {
            half8_t hv;
            hv[0] = (_Float16)ga[c].x;  hv[1] = (_Float16)ga[c].y;
            hv[2] = (_Float16)ga[c].z;  hv[3] = (_Float16)ga[c].w;
            hv[4] = (_Float16)gd[c].x;  hv[5] = (_Float16)gd[c].y;
            hv[6] = (_Float16)gd[c].z;  hv[7] = (_Float16)gd[c].w;
            *(half8_t*)&rows[wv][c * 8 + gi][gj * 8] = hv;  // ds_write_b128
        }
    }

    // ---- MFMA on valid tiles: S = U @ W1a (16x16x16 f16)
    float4_t acc[4] = {{0.f,0.f,0.f,0.f}, {0.f,0.f,0.f,0.f},
                       {0.f,0.f,0.f,0.f}, {0.f,0.f,0.f,0.f}};
    #pragma unroll
    for (int t = 0; t < 4; ++t) {
        if (t < nt) {               // uniform branch
            #pragma unroll
            for (int s = 0; s < 4; ++s) {
                const half4_t a =
                    *(const half4_t*)&rows[wv][t * 16 + h][s * 16 + q * 4];
                acc[t] = __builtin_amdgcn_mfma_f32_16x16x16f16(a, bfrag[s],
                                                               acc[t], 0, 0, 0);
            }
        }
    }

    // ---- scores: relu + w2, reduce over h (16 lanes sharing q)
    float sc[4][4];
    #pragma unroll
    for (int t = 0; t < 4; ++t) {
        if (t < nt) {
            #pragma unroll
            for (int r = 0; r < 4; ++r) {
                float v = fmaxf(acc[t][r] + ibh, 0.0f) * w2h;
                v += __shfl_xor(v, 1, 64);
                v += __shfl_xor(v, 2, 64);
                v += __shfl_xor(v, 4, 64);
                v += __shfl_xor(v, 8, 64);
                const int m = t * 16 + q * 4 + r;
                const bool vmask = (m < MM) && (m <= len);
                sc[t][r] = vmask ? (v + b2) : -INFINITY;
            }
        } else {
            #pragma unroll
            for (int r = 0; r < 4; ++r) sc[t][r] = -INFINITY;
        }
    }

    // ---- softmax over all 64 slots (each lane holds 16 distinct members)
    float mx = -INFINITY;
    #pragma unroll
    for (int t = 0; t < 4; ++t)
        #pragma unroll
        for (int r = 0; r < 4; ++r) mx = fmaxf(mx, sc[t][r]);
    mx = fmaxf(mx, __shfl_xor(mx, 16, 64));
    mx = fmaxf(mx, __shfl_xor(mx, 32, 64));

    float ew[4][4];
    float lsum = 0.0f;
    #pragma unroll
    for (int t = 0; t < 4; ++t) {
        #pragma unroll
        for (int r = 0; r < 4; ++r) {
            ew[t][r] = __expf(sc[t][r] - mx);     // exp(-inf)=0 for invalid
            lsum += ew[t][r];
        }
    }
    lsum += __shfl_xor(lsum, 16, 64);
    lsum += __shfl_xor(lsum, 32, 64);
    const float inv = 1.0f / lsum;

    if (h == 0) {   // lanes 0,16,32,48: one writer per member set
        #pragma unroll
        for (int t = 0; t < 4; ++t)
            #pragma unroll
            for (int r = 0; r < 4; ++r)
                wt[wv][t * 16 + q * 4 + r] = ew[t][r] * inv;
    }

    // ---- pool from LDS rows (lane-per-dim); same-wave LDS is in-order
    float g = 0.0f;
    #pragma unroll 4
    for (int m = 0; m < mcnt; ++m)
        g = fmaf(wt[wv][m], (float)rows[wv][m][lane], g);
    g += grp_d;

    // ---- predict MLP: new_e = [g*item, g, item] (192 -> 8 -> 1), lane-per-d
    const float elem = g * item_d;
    float p[PH];
    {
        const float* pa = pred_w1 + (size_t)lane * PH;      // L1-hot
        const float* pb = pred_w1 + (size_t)(DD + lane) * PH;
        const float* pc = pred_w1 + (size_t)(2 * DD + lane) * PH;
        #pragma unroll
        for (int jj = 0; jj < PH; ++jj)
            p[jj] = fmaf(elem, pa[jj], fmaf(g, pb[jj], item_d * pc[jj]));
    }
    #pragma unroll
    for (int off = 32; off > 0; off >>= 1) {
        #pragma unroll
        for (int jj = 0; jj < PH; ++jj) p[jj] += __shfl_xor(p[jj], off, 64);
    }

    if (lane == 0) {
        float acc2 = pred_b2[0];
        #pragma unroll
        for (int jj = 0; jj < PH; ++jj)
            acc2 = fmaf(fmaxf(p[jj] + pred_b1[jj], 0.0f), pred_w2[jj], acc2);
        out[b] = 1.0f / (1.0f + __expf(-acc2));
    }
}

extern "C" void kernel_launch(void* const* d_in, const int* in_sizes, int n_in,
                              void* d_out, int out_size, void* d_ws, size_t ws_size,
                              hipStream_t stream) {
    const int*   group_inputs   = (const int*)d_in[0];
    const int*   item_inputs    = (const int*)d_in[1];
    const int*   member_ids     = (const int*)d_in[2];
    const int*   member_lengths = (const int*)d_in[3];
    const float* user_table     = (const float*)d_in[4];
    const float* item_table     = (const float*)d_in[5];
    const float* group_table    = (const float*)d_in[6];
    const float* att_w1         = (const float*)d_in[7];
    const float* att_b1         = (const float*)d_in[8];
    const float* att_w2         = (const float*)d_in[9];
    const float* att_b2         = (const float*)d_in[10];
    const float* pred_w1        = (const float*)d_in[11];
    const float* pred_b1        = (const float*)d_in[12];
    const float* pred_w2        = (const float*)d_in[13];
    const float* pred_b2        = (const float*)d_in[14];
    float* out = (float*)d_out;

    const int B = in_sizes[0];
    (void)d_ws; (void)ws_size;   // unused: fills are unconditional (r4 measured)

    const int blocks = (B + WPB - 1) / WPB;
    agree_mfma<<<blocks, 256, 0, stream>>>(
        group_inputs, item_inputs, member_ids, member_lengths,
        user_table, item_table, group_table,
        att_w1, att_b1, att_w2, att_b2,
        pred_w1, pred_b1, pred_w2, pred_b2,
        out, B);
}

// Round 7
// 147.092 us; speedup vs baseline: 1.1282x; 1.0532x over previous
//
#include <hip/hip_runtime.h>
#include <math.h>

constexpr int MM = 50;    // members per group
constexpr int DD = 64;    // embedding dim
constexpr int HH = 16;    // attention hidden
constexpr int PH = 8;     // predict hidden
constexpr int WPB = 4;    // waves per block

typedef _Float16 half8_t __attribute__((ext_vector_type(8)));

// ============================================================================
// Kernel A (precompute, overlaps the harness's unconditional ws fills):
//   Uh = f16(user_table)            [nU][64]   12.8 MB
//   Us = f16(user_table @ W1a)      [nU][16]    3.2 MB  (score parts)
//   Ib = item_emb @ W1b + b1 (f32)  [B][16]     1.0 MB
// Amortizes the attention GEMV per-user (100K streaming rows) instead of
// per-sample-member (819K gathered rows).
// ============================================================================
__global__ __launch_bounds__(256) void precompute_kernel(
    const float* __restrict__ user_table,
    const float* __restrict__ item_table,
    const int*   __restrict__ item_inputs,
    const float* __restrict__ att_w1,   // [2D][H] row-major
    const float* __restrict__ att_b1,   // [H]
    _Float16* __restrict__ Uh,
    _Float16* __restrict__ Us,
    float*    __restrict__ Ib,
    int nU, int B, int userBlocks)
{
    const bool isU = (int)blockIdx.x < userBlocks;
    const float4* rp;
    const float*  w1;
    float acc[HH];
    int row = 0;

    if (isU) {
        row = (int)blockIdx.x * 256 + (int)threadIdx.x;
        if (row >= nU) return;
        rp  = (const float4*)(user_table + (size_t)row * DD);
        w1  = att_w1;
        #pragma unroll
        for (int j = 0; j < HH; ++j) acc[j] = 0.0f;
    } else {
        row = ((int)blockIdx.x - userBlocks) * 256 + (int)threadIdx.x;
        if (row >= B) return;
        const int item = item_inputs[row];
        rp  = (const float4*)(item_table + (size_t)item * DD);
        w1  = att_w1 + (size_t)DD * HH;
        #pragma unroll
        for (int j = 0; j < HH; ++j) acc[j] = att_b1[j];
    }

    half8_t hrow[8];                    // f16 copy of the row (users only)

    #pragma unroll
    for (int d4 = 0; d4 < DD / 4; ++d4) {
        const float4 x = rp[d4];
        const float* w = w1 + (size_t)(d4 * 4) * HH;       // uniform -> s_load
        #pragma unroll
        for (int j = 0; j < HH; ++j) {
            acc[j] = fmaf(x.x, w[0 * HH + j], acc[j]);
            acc[j] = fmaf(x.y, w[1 * HH + j], acc[j]);
            acc[j] = fmaf(x.z, w[2 * HH + j], acc[j]);
            acc[j] = fmaf(x.w, w[3 * HH + j], acc[j]);
        }
        const int hw = d4 >> 1, he = (d4 & 1) * 4;
        hrow[hw][he + 0] = (_Float16)x.x;
        hrow[hw][he + 1] = (_Float16)x.y;
        hrow[hw][he + 2] = (_Float16)x.z;
        hrow[hw][he + 3] = (_Float16)x.w;
    }

    if (isU) {
        #pragma unroll
        for (int w = 0; w < 8; ++w)
            *(half8_t*)(Uh + (size_t)row * DD + w * 8) = hrow[w];
        half8_t s0, s1;
        #pragma unroll
        for (int j = 0; j < 8; ++j) { s0[j] = (_Float16)acc[j];
                                      s1[j] = (_Float16)acc[8 + j]; }
        *(half8_t*)(Us + (size_t)row * HH)     = s0;
        *(half8_t*)(Us + (size_t)row * HH + 8) = s1;
    } else {
        float4* o4 = (float4*)(Ib + (size_t)row * HH);
        o4[0] = make_float4(acc[0],  acc[1],  acc[2],  acc[3]);
        o4[1] = make_float4(acc[4],  acc[5],  acc[6],  acc[7]);
        o4[2] = make_float4(acc[8],  acc[9],  acc[10], acc[11]);
        o4[3] = make_float4(acc[12], acc[13], acc[14], acc[15]);
    }
}

// ============================================================================
// Kernel B: wave-per-sample, NO MFMA, NO row-LDS (1KB bounce only -> high
// occupancy). ALL gathers issued upfront (row addresses depend only on ids):
//   phase-1: 32B/lane score-parts from Us (L2-hot, 3.2MB)
//   phase-2: 16B/lane/chunk f16 rows from Uh (valid chunks only, mean 3.6)
// Concurrency: ~5.6 loads/lane in flight x ~2x the occupancy of r6.
// ============================================================================
__global__ __launch_bounds__(256) void agree_main(
    const int* __restrict__ group_inputs,
    const int* __restrict__ item_inputs,
    const int* __restrict__ member_ids,
    const int* __restrict__ member_lengths,
    const float* __restrict__ item_table,
    const float* __restrict__ group_table,
    const float* __restrict__ att_w2,   // [H]
    const float* __restrict__ att_b2,   // [1]
    const float* __restrict__ pred_w1,  // [3D][8]
    const float* __restrict__ pred_b1,  // [8]
    const float* __restrict__ pred_w2,  // [8]
    const float* __restrict__ pred_b2,  // [1]
    const _Float16* __restrict__ Uh,    // [nU][64] f16
    const _Float16* __restrict__ Us,    // [nU][16] f16 score parts
    const float* __restrict__ Ib,       // [B][16] f32, b1 folded
    float* __restrict__ out,
    int B)
{
    __shared__ float gbuf[WPB][DD];     // 1 KB: pooled-g bounce

    const int lane = threadIdx.x & 63;
    const int wv   = threadIdx.x >> 6;
    const int b    = blockIdx.x * WPB + wv;
    if (b >= B) return;

    const int my_m  = (lane < MM) ? lane : (MM - 1);
    const int my_id = member_ids[b * MM + my_m];            // coalesced
    const int len      = member_lengths[b];                 // uniform
    const int item_idx = item_inputs[b];                    // uniform
    const int gid      = group_inputs[b];                   // uniform

    const float item_d = item_table[(unsigned)(item_idx * DD + lane)];
    const float grp_d  = group_table[(unsigned)(gid * DD + lane)];

    const int mcnt = (len < MM - 1 ? len : MM - 1) + 1;     // 1..50, uniform
    const int gch  = (mcnt + 7) >> 3;                       // chunks 1..7
    const int i    = lane >> 3;        // member sub-index within chunk
    const int j    = lane & 7;         // dim chunk (8 f16 = 16B)

    // ---- issue ALL gathers upfront (phase-1 + phase-2), fully in flight
    const half8_t ua = *(const half8_t*)(Us + (size_t)(unsigned)my_id * HH);
    const half8_t ub = *(const half8_t*)(Us + (size_t)(unsigned)my_id * HH + 8);

    half8_t r8[7];
    #pragma unroll
    for (int c = 0; c < 7; ++c) {
        if (c < gch) {                  // uniform branch
            const int id = __shfl(my_id, c * 8 + i, 64);
            r8[c] = *(const half8_t*)(Uh + (size_t)(unsigned)id * DD + j * 8);
        }
    }

    // ---- phase 1: score from f16 score-parts + precomputed Ib (uniform)
    const float* ib = Ib + (size_t)b * HH;                  // s_load
    float score = att_b2[0];
    #pragma unroll
    for (int k = 0; k < 8; ++k)
        score = fmaf(fmaxf((float)ua[k] + ib[k], 0.0f), att_w2[k], score);
    #pragma unroll
    for (int k = 0; k < 8; ++k)
        score = fmaf(fmaxf((float)ub[k] + ib[8 + k], 0.0f), att_w2[8 + k], score);

    const bool valid = (lane < MM) && (lane <= len);
    score = valid ? score : -INFINITY;

    // softmax over members (member 0 always valid)
    float mx = score;
    #pragma unroll
    for (int off = 32; off > 0; off >>= 1) mx = fmaxf(mx, __shfl_xor(mx, off, 64));
    const float e = valid ? __expf(score - mx) : 0.0f;
    float sum = e;
    #pragma unroll
    for (int off = 32; off > 0; off >>= 1) sum += __shfl_xor(sum, off, 64);
    const float wnorm = e / sum;        // 0 for invalid lanes

    // ---- phase 2: register pooling over prefetched rows
    float part[8];
    #pragma unroll
    for (int r = 0; r < 8; ++r) part[r] = 0.0f;
    #pragma unroll
    for (int c = 0; c < 7; ++c) {
        if (c < gch) {
            const float w = __shfl(wnorm, c * 8 + i, 64);   // 0 past mcnt
            #pragma unroll
            for (int r = 0; r < 8; ++r)
                part[r] = fmaf(w, (float)r8[c][r], part[r]);
        }
    }
    // reduce over member-sub axis i (lanes 8 apart share j)
    #pragma unroll
    for (int off = 8; off < 64; off <<= 1) {
        #pragma unroll
        for (int r = 0; r < 8; ++r) part[r] += __shfl_xor(part[r], off, 64);
    }
    // bounce to lane-per-dim: lanes 0..7 (i==0) hold dims j*8..j*8+7
    if (lane < 8) {
        float4* g4 = (float4*)&gbuf[wv][lane * 8];
        g4[0] = make_float4(part[0], part[1], part[2], part[3]);
        g4[1] = make_float4(part[4], part[5], part[6], part[7]);
    }
    const float g = gbuf[wv][lane] + grp_d;   // same-wave LDS, compiler waits

    // ---- predict MLP: new_e = [g*item, g, item] (192 -> 8 -> 1), lane-per-d
    const float elem = g * item_d;
    float p[PH];
    {
        const float* pa = pred_w1 + (size_t)lane * PH;      // L1-hot
        const float* pb = pred_w1 + (size_t)(DD + lane) * PH;
        const float* pc = pred_w1 + (size_t)(2 * DD + lane) * PH;
        #pragma unroll
        for (int jj = 0; jj < PH; ++jj)
            p[jj] = fmaf(elem, pa[jj], fmaf(g, pb[jj], item_d * pc[jj]));
    }
    #pragma unroll
    for (int off = 32; off > 0; off >>= 1) {
        #pragma unroll
        for (int jj = 0; jj < PH; ++jj) p[jj] += __shfl_xor(p[jj], off, 64);
    }

    if (lane == 0) {
        float acc = pred_b2[0];
        #pragma unroll
        for (int jj = 0; jj < PH; ++jj)
            acc = fmaf(fmaxf(p[jj] + pred_b1[jj], 0.0f), pred_w2[jj], acc);
        out[b] = 1.0f / (1.0f + __expf(-acc));
    }
}

// ============================================================================
// Fallback if ws too small (self-contained, verified structure, full fp32)
// ============================================================================
__global__ __launch_bounds__(256) void agree_fallback(
    const int* __restrict__ group_inputs,
    const int* __restrict__ item_inputs,
    const int* __restrict__ member_ids,
    const int* __restrict__ member_lengths,
    const float* __restrict__ user_table,
    const float* __restrict__ item_table,
    const float* __restrict__ group_table,
    const float* __restrict__ att_w1,
    const float* __restrict__ att_b1,
    const float* __restrict__ att_w2,
    const float* __restrict__ att_b2,
    const float* __restrict__ pred_w1,
    const float* __restrict__ pred_b1,
    const float* __restrict__ pred_w2,
    const float* __restrict__ pred_b2,
    float* __restrict__ out,
    int B)
{
    __shared__ float lds_wt[4][MM];
    __shared__ int   lds_id[4][MM];

    const int lane = threadIdx.x & 63;
    const int wave = threadIdx.x >> 6;
    const int b = blockIdx.x * 4 + wave;
    if (b >= B) return;

    const int my_m = (lane < MM) ? lane : (MM - 1);
    const int my_id = member_ids[b * MM + my_m];
    if (lane < MM) lds_id[wave][lane] = my_id;

    const int item_idx = item_inputs[b];
    const float item_d = item_table[(size_t)item_idx * DD + lane];

    float h[HH];
    {
        const float* w1row = att_w1 + (size_t)(DD + lane) * HH;
        #pragma unroll
        for (int j = 0; j < HH; ++j) h[j] = item_d * w1row[j];
        #pragma unroll
        for (int off = 32; off > 0; off >>= 1) {
            #pragma unroll
            for (int j = 0; j < HH; ++j) h[j] += __shfl_xor(h[j], off, 64);
        }
        #pragma unroll
        for (int j = 0; j < HH; ++j) h[j] += att_b1[j];
    }

    const float* myrow = user_table + (size_t)my_id * DD;
    #pragma unroll 4
    for (int d4 = 0; d4 < DD / 4; ++d4) {
        const float4 x = ((const float4*)myrow)[d4];
        const float* w1d = att_w1 + (size_t)(d4 * 4) * HH;
        #pragma unroll
        for (int j = 0; j < HH; ++j) {
            h[j] = fmaf(x.x, w1d[0 * HH + j], h[j]);
            h[j] = fmaf(x.y, w1d[1 * HH + j], h[j]);
            h[j] = fmaf(x.z, w1d[2 * HH + j], h[j]);
            h[j] = fmaf(x.w, w1d[3 * HH + j], h[j]);
        }
    }

    float score = att_b2[0];
    #pragma unroll
    for (int j = 0; j < HH; ++j) score = fmaf(fmaxf(h[j], 0.0f), att_w2[j], score);

    const int len = member_lengths[b];
    const bool valid = (lane < MM) && (lane <= len);
    score = valid ? score : -INFINITY;

    float mx = score;
    #pragma unroll
    for (int off = 32; off > 0; off >>= 1) mx = fmaxf(mx, __shfl_xor(mx, off, 64));
    float e = valid ? __expf(score - mx) : 0.0f;
    float sum = e;
    #pragma unroll
    for (int off = 32; off > 0; off >>= 1) sum += __shfl_xor(sum, off, 64);
    if (lane < MM) lds_wt[wave][lane] = e / sum;
    __builtin_amdgcn_s_waitcnt(0);

    const int mcnt = (len < MM - 1 ? len : MM - 1) + 1;
    float g = 0.0f;
    #pragma unroll 2
    for (int m = 0; m < mcnt; ++m) {
        g = fmaf(lds_wt[wave][m],
                 user_table[(size_t)lds_id[wave][m] * DD + lane], g);
    }
    const int gid = group_inputs[b];
    g += group_table[(size_t)gid * DD + lane];

    const float elem = g * item_d;
    float p[PH];
    {
        const float* pa = pred_w1 + (size_t)lane * PH;
        const float* pb = pred_w1 + (size_t)(DD + lane) * PH;
        const float* pc = pred_w1 + (size_t)(2 * DD + lane) * PH;
        #pragma unroll
        for (int j = 0; j < PH; ++j)
            p[j] = fmaf(elem, pa[j], fmaf(g, pb[j], item_d * pc[j]));
    }
    #pragma unroll
    for (int off = 32; off > 0; off >>= 1) {
        #pragma unroll
        for (int j = 0; j < PH; ++j) p[j] += __shfl_xor(p[j], off, 64);
    }

    if (lane == 0) {
        float acc = pred_b2[0];
        #pragma unroll
        for (int j = 0; j < PH; ++j)
            acc = fmaf(fmaxf(p[j] + pred_b1[j], 0.0f), pred_w2[j], acc);
        out[b] = 1.0f / (1.0f + __expf(-acc));
    }
}

extern "C" void kernel_launch(void* const* d_in, const int* in_sizes, int n_in,
                              void* d_out, int out_size, void* d_ws, size_t ws_size,
                              hipStream_t stream) {
    const int*   group_inputs   = (const int*)d_in[0];
    const int*   item_inputs    = (const int*)d_in[1];
    const int*   member_ids     = (const int*)d_in[2];
    const int*   member_lengths = (const int*)d_in[3];
    const float* user_table     = (const float*)d_in[4];
    const float* item_table     = (const float*)d_in[5];
    const float* group_table    = (const float*)d_in[6];
    const float* att_w1         = (const float*)d_in[7];
    const float* att_b1         = (const float*)d_in[8];
    const float* att_w2         = (const float*)d_in[9];
    const float* att_b2         = (const float*)d_in[10];
    const float* pred_w1        = (const float*)d_in[11];
    const float* pred_b1        = (const float*)d_in[12];
    const float* pred_w2        = (const float*)d_in[13];
    const float* pred_b2        = (const float*)d_in[14];
    float* out = (float*)d_out;

    const int B  = in_sizes[0];
    const int nU = in_sizes[4] / DD;
    const int blocks = (B + WPB - 1) / WPB;

    // ws layout: Uh [nU*64 f16] | Us [nU*16 f16] | Ib [B*16 f32]
    const size_t need = (size_t)nU * (DD + HH) * sizeof(_Float16)
                      + (size_t)B * HH * sizeof(float);

    if (ws_size >= need) {
        _Float16* Uh = (_Float16*)d_ws;
        _Float16* Us = Uh + (size_t)nU * DD;
        float*    Ib = (float*)(Us + (size_t)nU * HH);
        const int userBlocks = (nU + 255) / 256;
        const int itemBlocks = (B + 255) / 256;
        precompute_kernel<<<userBlocks + itemBlocks, 256, 0, stream>>>(
            user_table, item_table, item_inputs, att_w1, att_b1,
            Uh, Us, Ib, nU, B, userBlocks);
        agree_main<<<blocks, 256, 0, stream>>>(
            group_inputs, item_inputs, member_ids, member_lengths,
            item_table, group_table,
            att_w2, att_b2, pred_w1, pred_b1, pred_w2, pred_b2,
            Uh, Us, Ib, out, B);
    } else {
        agree_fallback<<<blocks, 256, 0, stream>>>(
            group_inputs, item_inputs, member_ids, member_lengths,
            user_table, item_table, group_table,
            att_w1, att_b1, att_w2, att_b2,
            pred_w1, pred_b1, pred_w2, pred_b2,
            out, B);
    }
}

// Round 8
// 144.846 us; speedup vs baseline: 1.1457x; 1.0155x over previous
//
#include <hip/hip_runtime.h>
#include <math.h>

constexpr int MM = 50;    // members per group
constexpr int DD = 64;    // embedding dim
constexpr int HH = 16;    // attention hidden
constexpr int PH = 8;     // predict hidden
constexpr int WPB = 4;    // waves per block

typedef _Float16 half8_t __attribute__((ext_vector_type(8)));

// ============================================================================
// Kernel A (precompute):
//   Uh = f16(user_table)            [nU][64]   12.8 MB
//   Us = f16(user_table @ W1a)      [nU][16]    3.2 MB  (score parts)
//   Ib = item_emb @ W1b + b1 (f32)  [B][16]     1.0 MB
// ============================================================================
__global__ __launch_bounds__(256) void precompute_kernel(
    const float* __restrict__ user_table,
    const float* __restrict__ item_table,
    const int*   __restrict__ item_inputs,
    const float* __restrict__ att_w1,   // [2D][H] row-major
    const float* __restrict__ att_b1,   // [H]
    _Float16* __restrict__ Uh,
    _Float16* __restrict__ Us,
    float*    __restrict__ Ib,
    int nU, int B, int userBlocks)
{
    const bool isU = (int)blockIdx.x < userBlocks;
    const float4* rp;
    const float*  w1;
    float acc[HH];
    int row = 0;

    if (isU) {
        row = (int)blockIdx.x * 256 + (int)threadIdx.x;
        if (row >= nU) return;
        rp  = (const float4*)(user_table + (size_t)row * DD);
        w1  = att_w1;
        #pragma unroll
        for (int j = 0; j < HH; ++j) acc[j] = 0.0f;
    } else {
        row = ((int)blockIdx.x - userBlocks) * 256 + (int)threadIdx.x;
        if (row >= B) return;
        const int item = item_inputs[row];
        rp  = (const float4*)(item_table + (size_t)item * DD);
        w1  = att_w1 + (size_t)DD * HH;
        #pragma unroll
        for (int j = 0; j < HH; ++j) acc[j] = att_b1[j];
    }

    half8_t hrow[8];                    // f16 copy of the row (users only)

    #pragma unroll
    for (int d4 = 0; d4 < DD / 4; ++d4) {
        const float4 x = rp[d4];
        const float* w = w1 + (size_t)(d4 * 4) * HH;       // uniform -> s_load
        #pragma unroll
        for (int j = 0; j < HH; ++j) {
            acc[j] = fmaf(x.x, w[0 * HH + j], acc[j]);
            acc[j] = fmaf(x.y, w[1 * HH + j], acc[j]);
            acc[j] = fmaf(x.z, w[2 * HH + j], acc[j]);
            acc[j] = fmaf(x.w, w[3 * HH + j], acc[j]);
        }
        const int hw = d4 >> 1, he = (d4 & 1) * 4;
        hrow[hw][he + 0] = (_Float16)x.x;
        hrow[hw][he + 1] = (_Float16)x.y;
        hrow[hw][he + 2] = (_Float16)x.z;
        hrow[hw][he + 3] = (_Float16)x.w;
    }

    if (isU) {
        #pragma unroll
        for (int w = 0; w < 8; ++w)
            *(half8_t*)(Uh + (size_t)row * DD + w * 8) = hrow[w];
        half8_t s0, s1;
        #pragma unroll
        for (int j = 0; j < 8; ++j) { s0[j] = (_Float16)acc[j];
                                      s1[j] = (_Float16)acc[8 + j]; }
        *(half8_t*)(Us + (size_t)row * HH)     = s0;
        *(half8_t*)(Us + (size_t)row * HH + 8) = s1;
    } else {
        float4* o4 = (float4*)(Ib + (size_t)row * HH);
        o4[0] = make_float4(acc[0],  acc[1],  acc[2],  acc[3]);
        o4[1] = make_float4(acc[4],  acc[5],  acc[6],  acc[7]);
        o4[2] = make_float4(acc[8],  acc[9],  acc[10], acc[11]);
        o4[3] = make_float4(acc[12], acc[13], acc[14], acc[15]);
    }
}

// ============================================================================
// Kernel B: wave-per-sample. r8: row gathers via global_load_lds (async
// global->LDS, ZERO VGPRs held by in-flight data). Chunk c's LDS dest is
// wave-uniform base (wv,c) + lane*16 -- exactly the HW pattern; per-lane
// global src = Uh row segment. All valid chunks issued upfront; score +
// softmax compute overlaps the fetch; one explicit vmcnt(0) before pooling
// (compiler cannot see async LDS writes). Pooling reads ds_read_b128 at
// lane*16 (2-way bank aliasing = free).
// ============================================================================
__global__ __launch_bounds__(256) void agree_main(
    const int* __restrict__ group_inputs,
    const int* __restrict__ item_inputs,
    const int* __restrict__ member_ids,
    const int* __restrict__ member_lengths,
    const float* __restrict__ item_table,
    const float* __restrict__ group_table,
    const float* __restrict__ att_w2,   // [H]
    const float* __restrict__ att_b2,   // [1]
    const float* __restrict__ pred_w1,  // [3D][8]
    const float* __restrict__ pred_b1,  // [8]
    const float* __restrict__ pred_w2,  // [8]
    const float* __restrict__ pred_b2,  // [1]
    const _Float16* __restrict__ Uh,    // [nU][64] f16
    const _Float16* __restrict__ Us,    // [nU][16] f16 score parts
    const float* __restrict__ Ib,       // [B][16] f32, b1 folded
    float* __restrict__ out,
    int B)
{
    __shared__ _Float16 rows[WPB][7 * 512];  // 7 chunks x (8 rows x 64 f16) = 28 KB
    __shared__ float    gbuf[WPB][DD];       // 1 KB pooled-g bounce

    const int lane = threadIdx.x & 63;
    const int wv   = threadIdx.x >> 6;
    const int b    = blockIdx.x * WPB + wv;
    if (b >= B) return;

    const int my_m  = (lane < MM) ? lane : (MM - 1);
    const int my_id = member_ids[b * MM + my_m];            // coalesced
    const int len      = member_lengths[b];                 // uniform
    const int item_idx = item_inputs[b];                    // uniform
    const int gid      = group_inputs[b];                   // uniform

    const int mcnt = (len < MM - 1 ? len : MM - 1) + 1;     // 1..50, uniform
    const int gch  = (mcnt + 7) >> 3;                       // chunks 1..7
    const int i    = lane >> 3;        // member sub-index within chunk
    const int j    = lane & 7;         // dim chunk (8 f16 = 16B)

    // ---- issue ALL row gathers async into LDS (no VGPR cost, all in flight)
    #pragma unroll
    for (int c = 0; c < 7; ++c) {
        if (c < gch) {                  // uniform branch
            const int id = __shfl(my_id, c * 8 + i, 64);
            const _Float16* src = Uh + (size_t)(unsigned)id * DD + j * 8;
            __builtin_amdgcn_global_load_lds(
                (const __attribute__((address_space(1))) unsigned*)src,
                (__attribute__((address_space(3))) unsigned*)&rows[wv][c * 512],
                16, 0, 0);
        }
    }

    // ---- overlap: score-part gather (VGPR), item/group rows
    const half8_t ua = *(const half8_t*)(Us + (size_t)(unsigned)my_id * HH);
    const half8_t ub = *(const half8_t*)(Us + (size_t)(unsigned)my_id * HH + 8);
    const float item_d = item_table[(unsigned)(item_idx * DD + lane)];
    const float grp_d  = group_table[(unsigned)(gid * DD + lane)];

    // ---- phase 1: score from f16 score-parts + precomputed Ib (uniform)
    const float* ib = Ib + (size_t)b * HH;                  // s_load
    float score = att_b2[0];
    #pragma unroll
    for (int k = 0; k < 8; ++k)
        score = fmaf(fmaxf((float)ua[k] + ib[k], 0.0f), att_w2[k], score);
    #pragma unroll
    for (int k = 0; k < 8; ++k)
        score = fmaf(fmaxf((float)ub[k] + ib[8 + k], 0.0f), att_w2[8 + k], score);

    const bool valid = (lane < MM) && (lane <= len);
    score = valid ? score : -INFINITY;

    // softmax over members (member 0 always valid)
    float mx = score;
    #pragma unroll
    for (int off = 32; off > 0; off >>= 1) mx = fmaxf(mx, __shfl_xor(mx, off, 64));
    const float e = valid ? __expf(score - mx) : 0.0f;
    float sum = e;
    #pragma unroll
    for (int off = 32; off > 0; off >>= 1) sum += __shfl_xor(sum, off, 64);
    const float wnorm = e / sum;        // 0 for invalid lanes

    // ---- drain async LDS writes, then pool from LDS (register partials)
    asm volatile("s_waitcnt vmcnt(0)" ::: "memory");

    float part[8];
    #pragma unroll
    for (int r = 0; r < 8; ++r) part[r] = 0.0f;
    #pragma unroll
    for (int c = 0; c < 7; ++c) {
        if (c < gch) {
            const float w = __shfl(wnorm, c * 8 + i, 64);   // 0 past mcnt
            const half8_t r8 = *(const half8_t*)&rows[wv][c * 512 + lane * 8];
            #pragma unroll
            for (int r = 0; r < 8; ++r)
                part[r] = fmaf(w, (float)r8[r], part[r]);
        }
    }
    // reduce over member-sub axis i (lanes 8 apart share j)
    #pragma unroll
    for (int off = 8; off < 64; off <<= 1) {
        #pragma unroll
        for (int r = 0; r < 8; ++r) part[r] += __shfl_xor(part[r], off, 64);
    }
    // bounce to lane-per-dim: lanes 0..7 (i==0) hold dims j*8..j*8+7
    if (lane < 8) {
        float4* g4 = (float4*)&gbuf[wv][lane * 8];
        g4[0] = make_float4(part[0], part[1], part[2], part[3]);
        g4[1] = make_float4(part[4], part[5], part[6], part[7]);
    }
    const float g = gbuf[wv][lane] + grp_d;   // same-wave LDS, compiler waits

    // ---- predict MLP: new_e = [g*item, g, item] (192 -> 8 -> 1), lane-per-d
    const float elem = g * item_d;
    float p[PH];
    {
        const float* pa = pred_w1 + (size_t)lane * PH;      // L1-hot
        const float* pb = pred_w1 + (size_t)(DD + lane) * PH;
        const float* pc = pred_w1 + (size_t)(2 * DD + lane) * PH;
        #pragma unroll
        for (int jj = 0; jj < PH; ++jj)
            p[jj] = fmaf(elem, pa[jj], fmaf(g, pb[jj], item_d * pc[jj]));
    }
    #pragma unroll
    for (int off = 32; off > 0; off >>= 1) {
        #pragma unroll
        for (int jj = 0; jj < PH; ++jj) p[jj] += __shfl_xor(p[jj], off, 64);
    }

    if (lane == 0) {
        float acc = pred_b2[0];
        #pragma unroll
        for (int jj = 0; jj < PH; ++jj)
            acc = fmaf(fmaxf(p[jj] + pred_b1[jj], 0.0f), pred_w2[jj], acc);
        out[b] = 1.0f / (1.0f + __expf(-acc));
    }
}

// ============================================================================
// Fallback if ws too small (self-contained, verified structure, full fp32)
// ============================================================================
__global__ __launch_bounds__(256) void agree_fallback(
    const int* __restrict__ group_inputs,
    const int* __restrict__ item_inputs,
    const int* __restrict__ member_ids,
    const int* __restrict__ member_lengths,
    const float* __restrict__ user_table,
    const float* __restrict__ item_table,
    const float* __restrict__ group_table,
    const float* __restrict__ att_w1,
    const float* __restrict__ att_b1,
    const float* __restrict__ att_w2,
    const float* __restrict__ att_b2,
    const float* __restrict__ pred_w1,
    const float* __restrict__ pred_b1,
    const float* __restrict__ pred_w2,
    const float* __restrict__ pred_b2,
    float* __restrict__ out,
    int B)
{
    __shared__ float lds_wt[4][MM];
    __shared__ int   lds_id[4][MM];

    const int lane = threadIdx.x & 63;
    const int wave = threadIdx.x >> 6;
    const int b = blockIdx.x * 4 + wave;
    if (b >= B) return;

    const int my_m = (lane < MM) ? lane : (MM - 1);
    const int my_id = member_ids[b * MM + my_m];
    if (lane < MM) lds_id[wave][lane] = my_id;

    const int item_idx = item_inputs[b];
    const float item_d = item_table[(size_t)item_idx * DD + lane];

    float h[HH];
    {
        const float* w1row = att_w1 + (size_t)(DD + lane) * HH;
        #pragma unroll
        for (int j = 0; j < HH; ++j) h[j] = item_d * w1row[j];
        #pragma unroll
        for (int off = 32; off > 0; off >>= 1) {
            #pragma unroll
            for (int j = 0; j < HH; ++j) h[j] += __shfl_xor(h[j], off, 64);
        }
        #pragma unroll
        for (int j = 0; j < HH; ++j) h[j] += att_b1[j];
    }

    const float* myrow = user_table + (size_t)my_id * DD;
    #pragma unroll 4
    for (int d4 = 0; d4 < DD / 4; ++d4) {
        const float4 x = ((const float4*)myrow)[d4];
        const float* w1d = att_w1 + (size_t)(d4 * 4) * HH;
        #pragma unroll
        for (int j = 0; j < HH; ++j) {
            h[j] = fmaf(x.x, w1d[0 * HH + j], h[j]);
            h[j] = fmaf(x.y, w1d[1 * HH + j], h[j]);
            h[j] = fmaf(x.z, w1d[2 * HH + j], h[j]);
            h[j] = fmaf(x.w, w1d[3 * HH + j], h[j]);
        }
    }

    float score = att_b2[0];
    #pragma unroll
    for (int j = 0; j < HH; ++j) score = fmaf(fmaxf(h[j], 0.0f), att_w2[j], score);

    const int len = member_lengths[b];
    const bool valid = (lane < MM) && (lane <= len);
    score = valid ? score : -INFINITY;

    float mx = score;
    #pragma unroll
    for (int off = 32; off > 0; off >>= 1) mx = fmaxf(mx, __shfl_xor(mx, off, 64));
    float e = valid ? __expf(score - mx) : 0.0f;
    float sum = e;
    #pragma unroll
    for (int off = 32; off > 0; off >>= 1) sum += __shfl_xor(sum, off, 64);
    if (lane < MM) lds_wt[wave][lane] = e / sum;
    __builtin_amdgcn_s_waitcnt(0);

    const int mcnt = (len < MM - 1 ? len : MM - 1) + 1;
    float g = 0.0f;
    #pragma unroll 2
    for (int m = 0; m < mcnt; ++m) {
        g = fmaf(lds_wt[wave][m],
                 user_table[(size_t)lds_id[wave][m] * DD + lane], g);
    }
    const int gid = group_inputs[b];
    g += group_table[(size_t)gid * DD + lane];

    const float elem = g * item_d;
    float p[PH];
    {
        const float* pa = pred_w1 + (size_t)lane * PH;
        const float* pb = pred_w1 + (size_t)(DD + lane) * PH;
        const float* pc = pred_w1 + (size_t)(2 * DD + lane) * PH;
        #pragma unroll
        for (int j = 0; j < PH; ++j)
            p[j] = fmaf(elem, pa[j], fmaf(g, pb[j], item_d * pc[j]));
    }
    #pragma unroll
    for (int off = 32; off > 0; off >>= 1) {
        #pragma unroll
        for (int j = 0; j < PH; ++j) p[j] += __shfl_xor(p[j], off, 64);
    }

    if (lane == 0) {
        float acc = pred_b2[0];
        #pragma unroll
        for (int j = 0; j < PH; ++j)
            acc = fmaf(fmaxf(p[j] + pred_b1[j], 0.0f), pred_w2[j], acc);
        out[b] = 1.0f / (1.0f + __expf(-acc));
    }
}

extern "C" void kernel_launch(void* const* d_in, const int* in_sizes, int n_in,
                              void* d_out, int out_size, void* d_ws, size_t ws_size,
                              hipStream_t stream) {
    const int*   group_inputs   = (const int*)d_in[0];
    const int*   item_inputs    = (const int*)d_in[1];
    const int*   member_ids     = (const int*)d_in[2];
    const int*   member_lengths = (const int*)d_in[3];
    const float* user_table     = (const float*)d_in[4];
    const float* item_table     = (const float*)d_in[5];
    const float* group_table    = (const float*)d_in[6];
    const float* att_w1         = (const float*)d_in[7];
    const float* att_b1         = (const float*)d_in[8];
    const float* att_w2         = (const float*)d_in[9];
    const float* att_b2         = (const float*)d_in[10];
    const float* pred_w1        = (const float*)d_in[11];
    const float* pred_b1        = (const float*)d_in[12];
    const float* pred_w2        = (const float*)d_in[13];
    const float* pred_b2        = (const float*)d_in[14];
    float* out = (float*)d_out;

    const int B  = in_sizes[0];
    const int nU = in_sizes[4] / DD;
    const int blocks = (B + WPB - 1) / WPB;

    // ws layout: Uh [nU*64 f16] | Us [nU*16 f16] | Ib [B*16 f32]
    const size_t need = (size_t)nU * (DD + HH) * sizeof(_Float16)
                      + (size_t)B * HH * sizeof(float);

    if (ws_size >= need) {
        _Float16* Uh = (_Float16*)d_ws;
        _Float16* Us = Uh + (size_t)nU * DD;
        float*    Ib = (float*)(Us + (size_t)nU * HH);
        const int userBlocks = (nU + 255) / 256;
        const int itemBlocks = (B + 255) / 256;
        precompute_kernel<<<userBlocks + itemBlocks, 256, 0, stream>>>(
            user_table, item_table, item_inputs, att_w1, att_b1,
            Uh, Us, Ib, nU, B, userBlocks);
        agree_main<<<blocks, 256, 0, stream>>>(
            group_inputs, item_inputs, member_ids, member_lengths,
            item_table, group_table,
            att_w2, att_b2, pred_w1, pred_b1, pred_w2, pred_b2,
            Uh, Us, Ib, out, B);
    } else {
        agree_fallback<<<blocks, 256, 0, stream>>>(
            group_inputs, item_inputs, member_ids, member_lengths,
            user_table, item_table, group_table,
            att_w1, att_b1, att_w2, att_b2,
            pred_w1, pred_b1, pred_w2, pred_b2,
            out, B);
    }
}